// Round 3
// baseline (787.451 us; speedup 1.0000x reference)
//
#include <hip/hip_runtime.h>

// SNN forward: 2 -> 10 (LIF) -> 4 (LIF), subtract-reset, 100 steps, batch 65536.
// One thread per batch element; recurrent state in registers.
// Write-bound: ~52 MB read, ~734 MB write -> HBM floor ~125 us @ 6.3 TB/s.
// spk1/mem1 (stride-40B scatter) are transposed through wave-private LDS slabs
// (no barriers: wave-internal DS ops are in-order) into contiguous float2 stores.
// spk2/mem2 are natively coalesced float4 stores.
// LPAD=14: lane word-stride 14 -> 4-way write conflicts (vs 8-way at 12),
// rows stay 8B-aligned for ds_*_b64. Depth-2 x prefetch covers ~900cy HBM latency.

#define T_STEPS 100
#define BATCH   65536
#define NI      2
#define NH      10
#define NO      4
#define LPAD    14

__global__ __launch_bounds__(256) void snn_fwd_kernel(
    const float* __restrict__ x,    // [T, B, NI]
    const float* __restrict__ W1,   // [NI, NH]
    const float* __restrict__ b1,   // [NH]
    const float* __restrict__ W2,   // [NH, NO]
    const float* __restrict__ b2,   // [NO]
    float* __restrict__ out)        // spk1_rec | mem1_rec | spk2_rec | mem2_rec
{
    // [arr: s1/m1][wave][lane][LPAD] — each wave touches only its own slab
    __shared__ float lds[2][4][64][LPAD];   // 28,672 B

    const int tid  = threadIdx.x;
    const int lane = tid & 63;
    const int wv   = tid >> 6;
    const int b    = blockIdx.x * 256 + tid;
    const int wb0  = blockIdx.x * 256 + wv * 64;   // wave's batch base

    // ---- weights (uniform; L2/scalar-cached) ----
    float w1[NI][NH], bb1[NH], w2[NH][NO], bb2[NO];
#pragma unroll
    for (int i = 0; i < NI; ++i)
#pragma unroll
        for (int h = 0; h < NH; ++h) w1[i][h] = W1[i * NH + h];
#pragma unroll
    for (int h = 0; h < NH; ++h) bb1[h] = b1[h];
#pragma unroll
    for (int h = 0; h < NH; ++h)
#pragma unroll
        for (int o = 0; o < NO; ++o) w2[h][o] = W2[h * NO + o];
#pragma unroll
    for (int o = 0; o < NO; ++o) bb2[o] = b2[o];

    // ---- recurrent state ----
    float mem1[NH], spk1[NH], mem2[NO], spk2[NO];
#pragma unroll
    for (int h = 0; h < NH; ++h) { mem1[h] = 0.0f; spk1[h] = 0.0f; }
#pragma unroll
    for (int o = 0; o < NO; ++o) { mem2[o] = 0.0f; spk2[o] = 0.0f; }

    // ---- output region offsets ----
    const size_t O_MEM1 = (size_t)T_STEPS * BATCH * NH;
    const size_t O_SPK2 = 2 * O_MEM1;
    const size_t O_MEM2 = O_SPK2 + (size_t)T_STEPS * BATCH * NO;

    float* p_s1 = out + (size_t)wb0 * NH;                 // wave-contiguous
    float* p_m1 = out + O_MEM1 + (size_t)wb0 * NH;
    float* p_s2 = out + O_SPK2 + (size_t)b * NO;          // per-thread float4
    float* p_m2 = out + O_MEM2 + (size_t)b * NO;
    const size_t stride1 = (size_t)BATCH * NH;
    const size_t stride2 = (size_t)BATCH * NO;

    // ---- t-invariant transpose offsets for pass k, this lane ----
    // qq: float offset in the wave's 640-float window; lw: padded LDS word offset
    int q[5], lw[5];
#pragma unroll
    for (int k = 0; k < 5; ++k) {
        const int qq = k * 128 + 2 * lane;        // even; qq%10 <= 8 so the
        q[k]  = qq;                               // float2 never crosses a row
        lw[k] = (qq / 10) * LPAD + (qq % 10);
    }
    const float* lsl0 = &lds[0][wv][0][0];
    const float* lsl1 = &lds[1][wv][0][0];

    const float2* x2 = (const float2*)x;          // [T][B] float2 (NI==2)
    float2 xv = x2[b];                            // t
    float2 xn = x2[(size_t)BATCH + b];            // t+1

    for (int t = 0; t < T_STEPS; ++t) {
        // depth-2 prefetch: issue load for t+2 now, consume at t+2
        const size_t pf = (t + 2 < T_STEPS) ? (size_t)(t + 2) * BATCH + b : (size_t)b;
        float2 xn2 = x2[pf];

        // ---- layer 1 (reference association; contraction -> fma) ----
        float s1new[NH];
#pragma unroll
        for (int h = 0; h < NH; ++h) {
            float c = xv.x * w1[0][h] + xv.y * w1[1][h] + bb1[h];
            float m = 0.5f * mem1[h] + c - spk1[h];   // BETA=0.5, THR=1.0
            mem1[h] = m;
            s1new[h] = (m > 1.0f) ? 1.0f : 0.0f;      // == (m-1>0), exact
        }

        // ---- layer 2 ----
        float c2[NO];
#pragma unroll
        for (int o = 0; o < NO; ++o) c2[o] = 0.0f;
#pragma unroll
        for (int h = 0; h < NH; ++h)
#pragma unroll
            for (int o = 0; o < NO; ++o)
                c2[o] += s1new[h] * w2[h][o];

        float s2new[NO];
#pragma unroll
        for (int o = 0; o < NO; ++o) {
            float c = c2[o] + bb2[o];
            float m = 0.5f * mem2[o] + c - spk2[o];
            mem2[o] = m;
            s2new[o] = (m > 1.0f) ? 1.0f : 0.0f;
        }

        // ---- wave-local LDS transpose of s1new/mem1 (b64 writes, no barrier) ----
#pragma unroll
        for (int h = 0; h < NH; h += 2) {
            *(float2*)&lds[0][wv][lane][h] = make_float2(s1new[h], s1new[h + 1]);
            *(float2*)&lds[1][wv][lane][h] = make_float2(mem1[h], mem1[h + 1]);
        }
        // same-wave DS ops are in-order; compiler inserts lgkmcnt before use
#pragma unroll
        for (int k = 0; k < 5; ++k) {
            const float2 v0 = *(const float2*)(lsl0 + lw[k]);
            const float2 v1 = *(const float2*)(lsl1 + lw[k]);
            *(float2*)(p_s1 + q[k]) = v0;   // 512 B/wave/instr, fully coalesced
            *(float2*)(p_m1 + q[k]) = v1;
        }

        // ---- layer-2 stores (16 B/lane contiguous) ----
        *(float4*)p_s2 = make_float4(s2new[0], s2new[1], s2new[2], s2new[3]);
        *(float4*)p_m2 = make_float4(mem2[0], mem2[1], mem2[2], mem2[3]);

        // ---- carry ----
#pragma unroll
        for (int h = 0; h < NH; ++h) spk1[h] = s1new[h];
#pragma unroll
        for (int o = 0; o < NO; ++o) spk2[o] = s2new[o];

        p_s1 += stride1; p_m1 += stride1;
        p_s2 += stride2; p_m2 += stride2;
        xv = xn; xn = xn2;
    }
}

extern "C" void kernel_launch(void* const* d_in, const int* in_sizes, int n_in,
                              void* d_out, int out_size, void* d_ws, size_t ws_size,
                              hipStream_t stream) {
    const float* x  = (const float*)d_in[0];
    const float* W1 = (const float*)d_in[1];
    const float* b1 = (const float*)d_in[2];
    const float* W2 = (const float*)d_in[3];
    const float* b2 = (const float*)d_in[4];
    float* out = (float*)d_out;

    dim3 block(256);
    dim3 grid(BATCH / 256);   // 256 blocks -> 1 per CU
    snn_fwd_kernel<<<grid, block, 0, stream>>>(x, W1, b1, W2, b2, out);
}

// Round 13
// 786.279 us; speedup vs baseline: 1.0015x; 1.0015x over previous
//
#include <hip/hip_runtime.h>

// SNN forward: 2 -> 10 (LIF) -> 4 (LIF), subtract-reset, 100 steps, batch 65536.
// Pair-split: 2 lanes per batch element (lane s=gtid&1 owns h in [5s,5s+5)).
// 131072 threads -> 2048 waves -> 2 waves/SIMD (2x round-3 occupancy).
// Layer-2 spikes exchanged via shfl_xor(.,1); both lanes run the identical
// h=0..9 accumulation -> bitwise-identical results to the round-3 kernel.
// s1/m1 go through a wave-private LDS transpose (double-buffered, 1-step
// software pipeline, no barriers: wave-internal DS ops are in-order) into
// fully coalesced float4+float stores. spk2/mem2: single exec-masked float4
// store per step (even lanes -> spk2 region, odd lanes -> mem2 region).
// Write-bound: ~52 MB read, ~734 MB write -> floor ~127 us @ 6.2 TB/s (fill-measured).

#define T_STEPS 100
#define BATCH   65536
#define NH      10
#define NO      4

__global__ __launch_bounds__(256) void snn_fwd_kernel(
    const float* __restrict__ x,    // [T, B, 2]
    const float* __restrict__ W1,   // [2, NH]
    const float* __restrict__ b1,   // [NH]
    const float* __restrict__ W2,   // [NH, NO]
    const float* __restrict__ b2,   // [NO]
    float* __restrict__ out)        // spk1_rec | mem1_rec | spk2_rec | mem2_rec
{
    // [t-parity buf][arr: s1/m1][wave][32 elem * 10 h] -- wave-private slabs
    __shared__ float lds[2][2][4][320];   // 40,960 B

    const int tid  = threadIdx.x;
    const int lane = tid & 63;
    const int wv   = tid >> 6;
    const int s    = lane & 1;                       // sub-lane: h-half owner
    const int gtid = blockIdx.x * 256 + tid;
    const int p    = gtid >> 1;                      // batch element
    const int wp0  = blockIdx.x * 128 + wv * 32;     // wave's first element

    // ---- weights ----
    const int h0 = 5 * s;
    float w1[2][5], bb1[5];
#pragma unroll
    for (int i = 0; i < 2; ++i)
#pragma unroll
        for (int j = 0; j < 5; ++j) w1[i][j] = W1[i * NH + h0 + j];
#pragma unroll
    for (int j = 0; j < 5; ++j) bb1[j] = b1[h0 + j];

    float w2[NH][NO], bb2[NO];                       // full copy on every lane
#pragma unroll
    for (int h = 0; h < NH; ++h)
#pragma unroll
        for (int o = 0; o < NO; ++o) w2[h][o] = W2[h * NO + o];
#pragma unroll
    for (int o = 0; o < NO; ++o) bb2[o] = b2[o];

    // ---- state ----
    float mem1[5], spk1[5], mem2[NO], spk2[NO];
#pragma unroll
    for (int j = 0; j < 5; ++j) { mem1[j] = 0.0f; spk1[j] = 0.0f; }
#pragma unroll
    for (int o = 0; o < NO; ++o) { mem2[o] = 0.0f; spk2[o] = 0.0f; }

    // ---- output pointers ----
    const size_t O_MEM1 = (size_t)T_STEPS * BATCH * NH;
    const size_t O_SPK2 = 2 * O_MEM1;
    const size_t O_MEM2 = O_SPK2 + (size_t)T_STEPS * BATCH * NO;
    const size_t stride1 = (size_t)BATCH * NH;
    const size_t stride2 = (size_t)BATCH * NO;

    float* p_s1  = out + (size_t)wp0 * NH;                 // step being STORED (t-1)
    float* p_m1  = out + O_MEM1 + (size_t)wp0 * NH;
    float* p_sm2 = out + (s ? O_MEM2 : O_SPK2) + (size_t)p * NO;  // step t

    const float2* x2 = (const float2*)x;
    float2 xv = x2[p];                        // x(0)
    float2 xa = x2[(size_t)BATCH + p];        // x(1)
    float2 xb = x2[2 * (size_t)BATCH + p];    // x(2)

    // ================= one step of compute =================
    auto compute_step = [&](float2 xin, float* s1new) {
#pragma unroll
        for (int j = 0; j < 5; ++j) {
            float c = xin.x * w1[0][j] + xin.y * w1[1][j] + bb1[j];
            float m = 0.5f * mem1[j] + c - spk1[j];    // BETA=0.5, THR=1.0
            mem1[j] = m;
            s1new[j] = (m > 1.0f) ? 1.0f : 0.0f;       // == (m-1>0), exact
            spk1[j]  = s1new[j];
        }
        // exchange partner's 5 spikes (floats, exact 0/1)
        float oth[5];
#pragma unroll
        for (int j = 0; j < 5; ++j) oth[j] = __shfl_xor(s1new[j], 1);
        float s1all[10];
#pragma unroll
        for (int j = 0; j < 5; ++j) {
            s1all[j]     = s ? oth[j]   : s1new[j];    // h = 0..4
            s1all[5 + j] = s ? s1new[j] : oth[j];      // h = 5..9
        }
        // layer 2 — identical order on both lanes (bitwise-deterministic)
        float c2[NO];
#pragma unroll
        for (int o = 0; o < NO; ++o) c2[o] = 0.0f;
#pragma unroll
        for (int h = 0; h < NH; ++h)
#pragma unroll
            for (int o = 0; o < NO; ++o)
                c2[o] = fmaf(s1all[h], w2[h][o], c2[o]);
        float4 v2;
        float s2new[NO], m2v[NO];
#pragma unroll
        for (int o = 0; o < NO; ++o) {
            float c = c2[o] + bb2[o];
            float m = 0.5f * mem2[o] + c - spk2[o];
            mem2[o] = m; m2v[o] = m;
            s2new[o] = (m > 1.0f) ? 1.0f : 0.0f;
            spk2[o]  = s2new[o];
        }
        v2.x = s ? m2v[0] : s2new[0];
        v2.y = s ? m2v[1] : s2new[1];
        v2.z = s ? m2v[2] : s2new[2];
        v2.w = s ? m2v[3] : s2new[3];
        *(float4*)p_sm2 = v2;                 // exec-masked: two 512B regions
        p_sm2 += stride2;
    };

    // ---------------- prologue: step 0 ----------------
    {
        float s1new[5];
        compute_step(xv, s1new);
        float* wr0 = &lds[0][0][wv][0];
        float* wr1 = &lds[0][1][wv][0];
#pragma unroll
        for (int j = 0; j < 5; ++j) {
            wr0[5 * lane + j] = s1new[j];     // flat [elem][h]; stride-5 lanes:
            wr1[5 * lane + j] = mem1[j];      // 2 lanes/bank -> conflict-free
        }
        xv = xa; xa = xb;
    }

    // ---------------- main loop: compute t, store t-1 ----------------
    for (int t = 1; t < T_STEPS; ++t) {
        const int bt = t & 1;
        // prefetch x(t+2)
        const size_t pf = (t + 2 < T_STEPS) ? ((size_t)(t + 2) * BATCH + p) : (size_t)p;
        xb = x2[pf];

        // issue transpose reads of step t-1 FIRST (latency hidden by compute)
        const float* rd0 = &lds[bt ^ 1][0][wv][0];
        const float* rd1 = &lds[bt ^ 1][1][wv][0];
        const float4 a0 = *(const float4*)(rd0 + 4 * lane);
        const float  a1 = rd0[256 + lane];
        const float4 b0 = *(const float4*)(rd1 + 4 * lane);
        const float  b1v = rd1[256 + lane];

        float s1new[5];
        compute_step(xv, s1new);

        // stage step t into the other buffer
        float* wr0 = &lds[bt][0][wv][0];
        float* wr1 = &lds[bt][1][wv][0];
#pragma unroll
        for (int j = 0; j < 5; ++j) {
            wr0[5 * lane + j] = s1new[j];
            wr1[5 * lane + j] = mem1[j];
        }

        // coalesced stores of step t-1 (1024B + 256B per array, line-aligned)
        *(float4*)(p_s1 + 4 * lane) = a0;
        p_s1[256 + lane]            = a1;
        *(float4*)(p_m1 + 4 * lane) = b0;
        p_m1[256 + lane]            = b1v;
        p_s1 += stride1; p_m1 += stride1;

        xv = xa; xa = xb;
    }

    // ---------------- epilogue: store step 99 ----------------
    {
        const float* rd0 = &lds[(T_STEPS - 1) & 1][0][wv][0];
        const float* rd1 = &lds[(T_STEPS - 1) & 1][1][wv][0];
        *(float4*)(p_s1 + 4 * lane) = *(const float4*)(rd0 + 4 * lane);
        p_s1[256 + lane]            = rd0[256 + lane];
        *(float4*)(p_m1 + 4 * lane) = *(const float4*)(rd1 + 4 * lane);
        p_m1[256 + lane]            = rd1[256 + lane];
    }
}

extern "C" void kernel_launch(void* const* d_in, const int* in_sizes, int n_in,
                              void* d_out, int out_size, void* d_ws, size_t ws_size,
                              hipStream_t stream) {
    const float* x  = (const float*)d_in[0];
    const float* W1 = (const float*)d_in[1];
    const float* b1 = (const float*)d_in[2];
    const float* W2 = (const float*)d_in[3];
    const float* b2 = (const float*)d_in[4];
    float* out = (float*)d_out;

    dim3 block(256);
    dim3 grid((BATCH * 2) / 256);   // 512 blocks -> 2/CU, 8 waves/CU, 2/SIMD
    snn_fwd_kernel<<<grid, block, 0, stream>>>(x, W1, b1, W2, b2, out);
}